// Round 9
// baseline (238.140 us; speedup 1.0000x reference)
//
#include <hip/hip_runtime.h>

// Problem constants: N=B*T=65536, D=256, K=1024
#define NTOT 65536
#define DDIM 256
#define KCB  1024
#define ND   16777216   // NTOT * DDIM

typedef __attribute__((ext_vector_type(4))) float f32x4;
typedef __attribute__((ext_vector_type(4))) int   i32x4;
typedef __attribute__((ext_vector_type(8))) int   i32x8;

__device__ static inline unsigned umax32(unsigned a, unsigned b) { return a > b ? a : b; }

// ---- fp32 -> fp8 e4m3fn (OCP), 4-at-a-time pack into an int (byte i = x_i) --
#if !__has_builtin(__builtin_amdgcn_cvt_pk_fp8_f32)
__device__ static inline unsigned f32_to_e4m3_1(float f) {
    unsigned u = __float_as_uint(f);
    unsigned s = (u >> 24) & 0x80u;
    unsigned a = u & 0x7fffffffu;
    float x = __uint_as_float(a);
    if (x >= 448.f) return s | 0x7Eu;
    if (x < 0.015625f) {                    // subnormal: multiples of 2^-9
        int m = (int)__builtin_rintf(x * 512.f);   // RNE, 0..8
        return s | (unsigned)m;             // m==8 -> 0x08 == 2^-6 normal, correct
    }
    unsigned r = (a + 0x7FFFFu + ((a >> 20) & 1u)) >> 20;   // RNE to 3 mantissa bits
    int E = (int)(r >> 3) - 127;
    unsigned code = ((unsigned)(E + 7) << 3) | (r & 7u);
    if (code >= 0x7Fu) code = 0x7Eu;
    return s | code;
}
#endif

__device__ static inline int pk4_fp8(float x0, float x1, float x2, float x3) {
#if __has_builtin(__builtin_amdgcn_cvt_pk_fp8_f32)
    int w = __builtin_amdgcn_cvt_pk_fp8_f32(x0, x1, 0, false);   // bytes 0,1
    w = __builtin_amdgcn_cvt_pk_fp8_f32(x2, x3, w, true);        // bytes 2,3
    return w;
#else
    return (int)(f32_to_e4m3_1(x0) | (f32_to_e4m3_1(x1) << 8) |
                 (f32_to_e4m3_1(x2) << 16) | (f32_to_e4m3_1(x3) << 24));
#endif
}

// ---------------- Prep: codebook -> fp8(x512) MX-fragments + biased esq ------
// Fragment layout for mfma_scale_f32_16x16x128_f8f6f4 (verified r5/r7/r8):
// lane l of a B-frag holds col = l&15, k = kf*128 + (l>>4)*32 + j (j=0..31),
// as two 16-B granules h. Byte addr:
//   ((cc*2 + kf)*2 + h)*1024 + ((q)*16 + (c&15))*16 + (k&15)
// esq stores 64 - 256*||e||^2. Also zeroes the packed-key combine array.
__global__ __launch_bounds__(256) void vq_prep_kernel(const float* __restrict__ cb,
                                                      char* __restrict__ cbf,
                                                      float* __restrict__ esq_scaled,
                                                      float* __restrict__ loss_out,
                                                      unsigned* __restrict__ keys) {
    int gid = blockIdx.x * 256 + threadIdx.x;   // 0..32767
    keys[gid] = 0u;                             // argmin combine via atomicMax
    keys[gid + 32768] = 0u;
    int c = gid >> 5;
    int j8 = gid & 31;                          // owns k = j8*8 .. j8*8+7
    const float* p = cb + (size_t)c * DDIM + j8 * 8;
    f32x4 x = *(const f32x4*)p;
    f32x4 y = *(const f32x4*)(p + 4);
    float ss = x[0]*x[0] + x[1]*x[1] + x[2]*x[2] + x[3]*x[3]
             + y[0]*y[0] + y[1]*y[1] + y[2]*y[2] + y[3]*y[3];
    #pragma unroll
    for (int m = 16; m; m >>= 1) ss += __shfl_xor(ss, m);   // reduce the 32 lanes of code c
    if (j8 == 0) esq_scaled[c] = 64.0f - 256.f * ss;        // pre-biased, pre-negated
    int w0 = pk4_fp8(512.f * x[0], 512.f * x[1], 512.f * x[2], 512.f * x[3]);
    int w1 = pk4_fp8(512.f * y[0], 512.f * y[1], 512.f * y[2], 512.f * y[3]);
    // k = j8*8: kf = j8>>4, q = (j8>>2)&3, h = (j8>>1)&1, byte = (j8&1)*8
    int cc = c >> 4, kf = j8 >> 4, q = (j8 >> 2) & 3, h = (j8 >> 1) & 1;
    size_t addr = (size_t)(((cc * 2 + kf) * 2 + h) * 1024)
                + (size_t)(q * 16 + (c & 15)) * 16 + (j8 & 1) * 8;
    *(long long*)(cbf + addr) = (long long)(unsigned)w0 | ((long long)w1 << 32);
    if (gid == 0) loss_out[0] = 0.f;
}

// ---------------- Kernel 1: argmin, 8192 one-wave blocks ---------------------
// Wave = 32 rows x 256 cols. cg = bid>>11 (time-separated passes over z: z is
// read 4x but stays L3-resident; HBM fetches it once). Zero LDS, zero
// barriers, zero block coupling: cross-wave argmin combine is a global
// atomicMax on packed keys (u32 max == argmin incl. lowest-index tie-break).
// r8 evidence: K-loop stall scales as 1/waves-per-SIMD (2250->1140 cyc/step
// from 1->2 waves); this grid gives 4-5 waves/SIMD with a ~3% drain tail.
// Packed key: acc init = 64-256||e||^2 => final acc = s+64 > 0;
// key = (as_uint & ~1023) | (1023-col).
__global__ __launch_bounds__(64, 4) void vq_argmin_kernel(const float* __restrict__ z,
                                                          const char* __restrict__ cbf,
                                                          const float* __restrict__ esq_scaled,
                                                          unsigned* __restrict__ keys,
                                                          float* __restrict__ zsq_out) {
    const int lane = threadIdx.x;
    const int bid  = blockIdx.x;
    const int cg   = bid >> 11;          // column group: cols cg*256..cg*256+255
    const int base = (bid & 2047) * 32;  // this wave's 32 rows
    const int q    = lane >> 4;
    const int ln   = lane & 15;

    // B chunks 0,1 prefetch (L2-resident after first touch); esq 2 ahead
    const char* bbase = cbf + (size_t)cg * 65536 + (size_t)lane * 16;
    i32x4 B0[4], B1[4];                 // [kf*2 + h]
    #pragma unroll
    for (int j = 0; j < 4; ++j) {
        B0[j] = *(const i32x4*)(bbase + j * 1024);
        B1[j] = *(const i32x4*)(bbase + 4096 + j * 1024);
    }
    const float* ebase = esq_scaled + cg * 256;
    float e_cur = ebase[ln];
    float e_nxt = ebase[16 + ln];

    // ---- A: per-lane direct load + in-register fp8 pack + row ||z||^2 ------
    // lane(q,ln) holds rows rf*16+ln (rf=0,1), k = kf*128 + q*32 + j.
    i32x8 av[2][2];
    float zsq[2];
    #pragma unroll
    for (int rf = 0; rf < 2; ++rf) {
        float sq = 0.f;
        #pragma unroll
        for (int kf = 0; kf < 2; ++kf) {
            const float* ap = z + (size_t)(base + rf * 16 + ln) * DDIM + kf * 128 + q * 32;
            int wrd[8];
            #pragma unroll
            for (int j = 0; j < 8; ++j) {
                f32x4 x = *(const f32x4*)(ap + j * 4);
                sq += x[0]*x[0] + x[1]*x[1] + x[2]*x[2] + x[3]*x[3];
                wrd[j] = pk4_fp8(x[0], x[1], x[2], x[3]);
            }
            i32x8 v;
            #pragma unroll
            for (int j = 0; j < 8; ++j) v[j] = wrd[j];
            av[rf][kf] = v;
        }
        sq += __shfl_xor(sq, 16);
        sq += __shfl_xor(sq, 32);       // sum the 4 q-slices: full row sum
        zsq[rf] = sq;
    }
    // store ||z||^2 once (cg 0 only) for the gather kernel's loss pass
    if (cg == 0 && q == 0) {
        zsq_out[base + ln]      = zsq[0];
        zsq_out[base + 16 + ln] = zsq[1];
    }

    unsigned best[8];
    #pragma unroll
    for (int i = 0; i < 8; ++i) best[i] = 0u;
    const int colinv0 = 1023 - cg * 256 - ln;

    // ---- K-loop: 16 chunks of 16 cols, distance-2 ping-pong, no barriers ---
#define VQ_STEP(Bb_, C_)                                                       \
    {                                                                          \
        i32x8 bv0, bv1;                                                        \
        ((i32x4*)&bv0)[0] = Bb_[0]; ((i32x4*)&bv0)[1] = Bb_[1];                \
        ((i32x4*)&bv1)[0] = Bb_[2]; ((i32x4*)&bv1)[1] = Bb_[3];                \
        _Pragma("unroll")                                                      \
        for (int j = 0; j < 4; ++j)                                            \
            Bb_[j] = *(const i32x4*)(bbase + (size_t)(((C_) + 2) & 15) * 4096 + j * 1024); \
        const float e4 = e_cur;                                                \
        e_cur = e_nxt;                                                         \
        e_nxt = ebase[(((C_) + 2) & 15) * 16 + ln];                            \
        f32x4 ac0 = {e4, e4, e4, e4};                                          \
        f32x4 ac1 = ac0;                                                       \
        __builtin_amdgcn_s_setprio(1);                                         \
        ac0 = __builtin_amdgcn_mfma_scale_f32_16x16x128_f8f6f4(av[0][0], bv0, ac0, 0, 0, 0, 0x7F7F7F7F, 0, 0x7F7F7F7F); \
        ac1 = __builtin_amdgcn_mfma_scale_f32_16x16x128_f8f6f4(av[1][0], bv0, ac1, 0, 0, 0, 0x7F7F7F7F, 0, 0x7F7F7F7F); \
        ac0 = __builtin_amdgcn_mfma_scale_f32_16x16x128_f8f6f4(av[0][1], bv1, ac0, 0, 0, 0, 0x7F7F7F7F, 0, 0x7F7F7F7F); \
        ac1 = __builtin_amdgcn_mfma_scale_f32_16x16x128_f8f6f4(av[1][1], bv1, ac1, 0, 0, 0, 0x7F7F7F7F, 0, 0x7F7F7F7F); \
        __builtin_amdgcn_s_setprio(0);                                         \
        const unsigned ci = (unsigned)(colinv0 - (C_) * 16);                   \
        _Pragma("unroll")                                                      \
        for (int i = 0; i < 4; ++i) {                                          \
            best[i]     = umax32(best[i],     (__float_as_uint(ac0[i]) & 0xFFFFFC00u) | ci); \
            best[4 + i] = umax32(best[4 + i], (__float_as_uint(ac1[i]) & 0xFFFFFC00u) | ci); \
        }                                                                      \
    }

    for (int c = 0; c < 16; c += 2) {
        VQ_STEP(B0, c);
        VQ_STEP(B1, c + 1);     // wrap loads re-read chunks 0/1: harmless
    }
#undef VQ_STEP

    // ---- in-wave argmin reduce over the 16 ln-lanes of each q-group --------
    #pragma unroll
    for (int m = 1; m < 16; m <<= 1)
        #pragma unroll
        for (int i = 0; i < 8; ++i)
            best[i] = umax32(best[i], (unsigned)__shfl_xor((int)best[i], m));

    // ---- cross-wave combine: device-scope atomicMax on packed keys ---------
    // lane (q, ln=q*4+i) owns rows base + rf*16 + q*4 + i.
    if ((ln >> 2) == q) {
        const int i = ln & 3;
        atomicMax(&keys[base + q * 4 + i],      best[i]);
        atomicMax(&keys[base + 16 + q * 4 + i], best[4 + i]);
    }
}

// ---------------- Kernel 2: loss + gather + streaming NT store ---------------
// 1024 blocks x 256 thr, tiny VGPR -> high residency, saturates write BW.
// Reads keys+zsq (512KB) + cb (1MB, L2-resident), writes z_q (64MB, NT).
// Loss reconstructed from the winning key: ||z-e*||^2 = ||z||^2 - s/256.
__global__ __launch_bounds__(256) void vq_gather_kernel(const float* __restrict__ cb,
                                                        const unsigned* __restrict__ keys,
                                                        const float* __restrict__ zsq,
                                                        float* __restrict__ out) {
    __shared__ int k_s[64];
    const int tid = threadIdx.x;
    const int b0 = blockIdx.x * 64;
    if (tid < 64) {
        unsigned u = keys[b0 + tid];
        k_s[tid] = 1023 - (int)(u & 1023u);
        // midpoint-reconstruct the truncated score: s+64
        float sval = __uint_as_float((u & 0xFFFFFC00u) | 0x200u) - 64.0f;
        float lsum = zsq[b0 + tid] - sval * 0.00390625f;
        #pragma unroll
        for (int off = 32; off; off >>= 1) lsum += __shfl_down(lsum, off);
        if (tid == 0) atomicAdd(out + ND, lsum * (1.0f / (float)ND));
    }
    __syncthreads();
    #pragma unroll
    for (int i = 0; i < 16; ++i) {
        int item = tid + i * 256;
        int row = item >> 6, c4 = item & 63;
        int k = k_s[row];
        f32x4 v = *(const f32x4*)(cb + (size_t)k * DDIM + c4 * 4);
        __builtin_nontemporal_store(v, (f32x4*)(out + (size_t)(b0 + row) * DDIM + c4 * 4));
    }
}

extern "C" void kernel_launch(void* const* d_in, const int* in_sizes, int n_in,
                              void* d_out, int out_size, void* d_ws, size_t ws_size,
                              hipStream_t stream) {
    const float* z  = (const float*)d_in[0];   // z_e, 65536 x 256 fp32
    const float* cb = (const float*)d_in[1];   // codebook, 1024 x 256 fp32
    float* out = (float*)d_out;                // z_q (16777216) ++ loss (1)

    float*    esq_scaled = (float*)d_ws;                                  // 4 KB
    char*     cb_frag    = (char*)d_ws + 4096;                            // 256 KB
    unsigned* keys_ws    = (unsigned*)((char*)d_ws + 4096 + 262144);      // 256 KB
    float*    zsq_ws     = (float*)((char*)d_ws + 4096 + 2 * 262144);     // 256 KB

    vq_prep_kernel<<<128, 256, 0, stream>>>(cb, cb_frag, esq_scaled, out + ND, keys_ws);
    vq_argmin_kernel<<<8192, 64, 0, stream>>>(z, cb_frag, esq_scaled, keys_ws, zsq_ws);
    vq_gather_kernel<<<1024, 256, 0, stream>>>(cb, keys_ws, zsq_ws, out);
}

// Round 10
// 158.456 us; speedup vs baseline: 1.5029x; 1.5029x over previous
//
#include <hip/hip_runtime.h>

// Problem constants: N=B*T=65536, D=256, K=1024
#define NTOT 65536
#define DDIM 256
#define KCB  1024
#define ND   16777216   // NTOT * DDIM

typedef __attribute__((ext_vector_type(4))) float f32x4;
typedef __attribute__((ext_vector_type(4))) int   i32x4;
typedef __attribute__((ext_vector_type(8))) int   i32x8;

__device__ static inline unsigned umax32(unsigned a, unsigned b) { return a > b ? a : b; }

// ---- fp32 -> fp8 e4m3fn (OCP), 4-at-a-time pack into an int (byte i = x_i) --
#if !__has_builtin(__builtin_amdgcn_cvt_pk_fp8_f32)
__device__ static inline unsigned f32_to_e4m3_1(float f) {
    unsigned u = __float_as_uint(f);
    unsigned s = (u >> 24) & 0x80u;
    unsigned a = u & 0x7fffffffu;
    float x = __uint_as_float(a);
    if (x >= 448.f) return s | 0x7Eu;
    if (x < 0.015625f) {                    // subnormal: multiples of 2^-9
        int m = (int)__builtin_rintf(x * 512.f);   // RNE, 0..8
        return s | (unsigned)m;             // m==8 -> 0x08 == 2^-6 normal, correct
    }
    unsigned r = (a + 0x7FFFFu + ((a >> 20) & 1u)) >> 20;   // RNE to 3 mantissa bits
    int E = (int)(r >> 3) - 127;
    unsigned code = ((unsigned)(E + 7) << 3) | (r & 7u);
    if (code >= 0x7Fu) code = 0x7Eu;
    return s | code;
}
#endif

__device__ static inline int pk4_fp8(float x0, float x1, float x2, float x3) {
#if __has_builtin(__builtin_amdgcn_cvt_pk_fp8_f32)
    int w = __builtin_amdgcn_cvt_pk_fp8_f32(x0, x1, 0, false);   // bytes 0,1
    w = __builtin_amdgcn_cvt_pk_fp8_f32(x2, x3, w, true);        // bytes 2,3
    return w;
#else
    return (int)(f32_to_e4m3_1(x0) | (f32_to_e4m3_1(x1) << 8) |
                 (f32_to_e4m3_1(x2) << 16) | (f32_to_e4m3_1(x3) << 24));
#endif
}

// ---------------- Prep: codebook -> fp8(x512) MX-fragments + biased esq ------
// Fragment layout for mfma_scale_f32_16x16x128_f8f6f4 (verified r5/r7/r8/r9):
// lane l of a B-frag holds col = l&15, k = kf*128 + (l>>4)*32 + j (j=0..31),
// as two 16-B granules h. Byte addr:
//   ((cc*2 + kf)*2 + h)*1024 + ((q)*16 + (c&15))*16 + (k&15)
// esq stores 64 - 256*||e||^2. Also zeroes the packed-key combine array.
__global__ __launch_bounds__(256) void vq_prep_kernel(const float* __restrict__ cb,
                                                      char* __restrict__ cbf,
                                                      float* __restrict__ esq_scaled,
                                                      float* __restrict__ loss_out,
                                                      unsigned* __restrict__ keys) {
    int gid = blockIdx.x * 256 + threadIdx.x;   // 0..32767
    keys[gid] = 0u;                             // argmin combine via atomicMax
    keys[gid + 32768] = 0u;
    int c = gid >> 5;
    int j8 = gid & 31;                          // owns k = j8*8 .. j8*8+7
    const float* p = cb + (size_t)c * DDIM + j8 * 8;
    f32x4 x = *(const f32x4*)p;
    f32x4 y = *(const f32x4*)(p + 4);
    float ss = x[0]*x[0] + x[1]*x[1] + x[2]*x[2] + x[3]*x[3]
             + y[0]*y[0] + y[1]*y[1] + y[2]*y[2] + y[3]*y[3];
    #pragma unroll
    for (int m = 16; m; m >>= 1) ss += __shfl_xor(ss, m);   // reduce the 32 lanes of code c
    if (j8 == 0) esq_scaled[c] = 64.0f - 256.f * ss;        // pre-biased, pre-negated
    int w0 = pk4_fp8(512.f * x[0], 512.f * x[1], 512.f * x[2], 512.f * x[3]);
    int w1 = pk4_fp8(512.f * y[0], 512.f * y[1], 512.f * y[2], 512.f * y[3]);
    // k = j8*8: kf = j8>>4, q = (j8>>2)&3, h = (j8>>1)&1, byte = (j8&1)*8
    int cc = c >> 4, kf = j8 >> 4, q = (j8 >> 2) & 3, h = (j8 >> 1) & 1;
    size_t addr = (size_t)(((cc * 2 + kf) * 2 + h) * 1024)
                + (size_t)(q * 16 + (c & 15)) * 16 + (j8 & 1) * 8;
    *(long long*)(cbf + addr) = (long long)(unsigned)w0 | ((long long)w1 << 32);
    if (gid == 0) loss_out[0] = 0.f;
}

// ---------------- Kernel 1: argmin, 1024 blocks, 4 waves/SIMD ----------------
// 1024 blocks x 256 thr, ALL co-resident (4 blocks/CU; VGPR ~72 at (256,2) --
// bounds kept at the r8-proven codegen, residency comes from the GRID, not
// launch_bounds; r6/r9 showed forcing the bound causes spill). Wave = 32 rows
// x 512 cols; cg = bid>>9. Blocks b and b+512 touch the SAME rows on the SAME
// XCD (512%8==0) -> z L2-shared, HBM reads z once. Zero LDS, zero barriers;
// cross-wave argmin combine = device atomicMax on packed keys (u32 max ==
// argmin incl. lowest-index tie-break; verified r9). r7->r8 evidence: K-loop
// stall scales 1/waves-per-SIMD (2250->1140 cyc/chunk); 4/SIMD -> ~570.
// Packed key: acc init = 64-256||e||^2 => final acc = s+64 > 0;
// key = (as_uint & ~1023) | (1023-col).
__global__ __launch_bounds__(256, 2) void vq_argmin_kernel(const float* __restrict__ z,
                                                           const char* __restrict__ cbf,
                                                           const float* __restrict__ esq_scaled,
                                                           unsigned* __restrict__ keys,
                                                           float* __restrict__ zsq_out) {
    const int tid  = threadIdx.x;
    const int lane = tid & 63;
    const int wv   = tid >> 6;
    const int bid  = blockIdx.x;
    const int cg   = bid >> 9;                        // cols cg*512 .. cg*512+511
    const int base = ((bid & 511) * 4 + wv) * 32;     // this wave's 32 rows
    const int q    = lane >> 4;
    const int ln   = lane & 15;

    // B chunks 0,1 prefetch (L2-resident after first touch); esq 2 ahead.
    // cg region: 32 chunks x 4096 B = 128 KB.
    const char* bbase = cbf + (size_t)cg * 131072 + (size_t)lane * 16;
    i32x4 B0[4], B1[4];                 // [kf*2 + h]
    #pragma unroll
    for (int j = 0; j < 4; ++j) {
        B0[j] = *(const i32x4*)(bbase + j * 1024);
        B1[j] = *(const i32x4*)(bbase + 4096 + j * 1024);
    }
    const float* ebase = esq_scaled + cg * 512;
    float e_cur = ebase[ln];
    float e_nxt = ebase[16 + ln];

    // ---- A: per-lane direct load + in-register fp8 pack + row ||z||^2 ------
    // lane(q,ln) holds rows rf*16+ln (rf=0,1), k = kf*128 + q*32 + j.
    i32x8 av[2][2];
    float zsq[2];
    #pragma unroll
    for (int rf = 0; rf < 2; ++rf) {
        float sq = 0.f;
        #pragma unroll
        for (int kf = 0; kf < 2; ++kf) {
            const float* ap = z + (size_t)(base + rf * 16 + ln) * DDIM + kf * 128 + q * 32;
            int wrd[8];
            #pragma unroll
            for (int j = 0; j < 8; ++j) {
                f32x4 x = *(const f32x4*)(ap + j * 4);
                sq += x[0]*x[0] + x[1]*x[1] + x[2]*x[2] + x[3]*x[3];
                wrd[j] = pk4_fp8(x[0], x[1], x[2], x[3]);
            }
            i32x8 v;
            #pragma unroll
            for (int j = 0; j < 8; ++j) v[j] = wrd[j];
            av[rf][kf] = v;
        }
        sq += __shfl_xor(sq, 16);
        sq += __shfl_xor(sq, 32);       // sum the 4 q-slices: full row sum
        zsq[rf] = sq;
    }
    // store ||z||^2 once (cg 0 only) for the gather kernel's loss pass
    if (cg == 0 && q == 0) {
        zsq_out[base + ln]      = zsq[0];
        zsq_out[base + 16 + ln] = zsq[1];
    }

    unsigned best[8];
    #pragma unroll
    for (int i = 0; i < 8; ++i) best[i] = 0u;
    const int colinv0 = 1023 - cg * 512 - ln;

    // ---- K-loop: 32 chunks of 16 cols, distance-2 ping-pong, no barriers ---
#define VQ_STEP(Bb_, C_)                                                       \
    {                                                                          \
        i32x8 bv0, bv1;                                                        \
        ((i32x4*)&bv0)[0] = Bb_[0]; ((i32x4*)&bv0)[1] = Bb_[1];                \
        ((i32x4*)&bv1)[0] = Bb_[2]; ((i32x4*)&bv1)[1] = Bb_[3];                \
        _Pragma("unroll")                                                      \
        for (int j = 0; j < 4; ++j)                                            \
            Bb_[j] = *(const i32x4*)(bbase + (size_t)(((C_) + 2) & 31) * 4096 + j * 1024); \
        const float e4 = e_cur;                                                \
        e_cur = e_nxt;                                                         \
        e_nxt = ebase[(((C_) + 2) & 31) * 16 + ln];                            \
        f32x4 ac0 = {e4, e4, e4, e4};                                          \
        f32x4 ac1 = ac0;                                                       \
        __builtin_amdgcn_s_setprio(1);                                         \
        ac0 = __builtin_amdgcn_mfma_scale_f32_16x16x128_f8f6f4(av[0][0], bv0, ac0, 0, 0, 0, 0x7F7F7F7F, 0, 0x7F7F7F7F); \
        ac1 = __builtin_amdgcn_mfma_scale_f32_16x16x128_f8f6f4(av[1][0], bv0, ac1, 0, 0, 0, 0x7F7F7F7F, 0, 0x7F7F7F7F); \
        ac0 = __builtin_amdgcn_mfma_scale_f32_16x16x128_f8f6f4(av[0][1], bv1, ac0, 0, 0, 0, 0x7F7F7F7F, 0, 0x7F7F7F7F); \
        ac1 = __builtin_amdgcn_mfma_scale_f32_16x16x128_f8f6f4(av[1][1], bv1, ac1, 0, 0, 0, 0x7F7F7F7F, 0, 0x7F7F7F7F); \
        __builtin_amdgcn_s_setprio(0);                                         \
        const unsigned ci = (unsigned)(colinv0 - (C_) * 16);                   \
        _Pragma("unroll")                                                      \
        for (int i = 0; i < 4; ++i) {                                          \
            best[i]     = umax32(best[i],     (__float_as_uint(ac0[i]) & 0xFFFFFC00u) | ci); \
            best[4 + i] = umax32(best[4 + i], (__float_as_uint(ac1[i]) & 0xFFFFFC00u) | ci); \
        }                                                                      \
    }

    for (int c = 0; c < 32; c += 2) {
        VQ_STEP(B0, c);
        VQ_STEP(B1, c + 1);     // wrap loads re-read chunks 0/1: harmless
    }
#undef VQ_STEP

    // ---- in-wave argmin reduce over the 16 ln-lanes of each q-group --------
    #pragma unroll
    for (int m = 1; m < 16; m <<= 1)
        #pragma unroll
        for (int i = 0; i < 8; ++i)
            best[i] = umax32(best[i], (unsigned)__shfl_xor((int)best[i], m));

    // ---- cross-wave combine: device-scope atomicMax on packed keys ---------
    // lane (q, ln=q*4+i) owns rows base + rf*16 + q*4 + i.
    if ((ln >> 2) == q) {
        const int i = ln & 3;
        atomicMax(&keys[base + q * 4 + i],      best[i]);
        atomicMax(&keys[base + 16 + q * 4 + i], best[4 + i]);
    }
}

// ---------------- Kernel 2: loss + gather + streaming NT store ---------------
// 1024 blocks x 256 thr, tiny VGPR -> high residency, saturates write BW.
// Reads keys+zsq (512KB) + cb (1MB, L2-resident), writes z_q (64MB, NT).
// Loss reconstructed from the winning key: ||z-e*||^2 = ||z||^2 - s/256.
__global__ __launch_bounds__(256) void vq_gather_kernel(const float* __restrict__ cb,
                                                        const unsigned* __restrict__ keys,
                                                        const float* __restrict__ zsq,
                                                        float* __restrict__ out) {
    __shared__ int k_s[64];
    const int tid = threadIdx.x;
    const int b0 = blockIdx.x * 64;
    if (tid < 64) {
        unsigned u = keys[b0 + tid];
        k_s[tid] = 1023 - (int)(u & 1023u);
        // midpoint-reconstruct the truncated score: s+64
        float sval = __uint_as_float((u & 0xFFFFFC00u) | 0x200u) - 64.0f;
        float lsum = zsq[b0 + tid] - sval * 0.00390625f;
        #pragma unroll
        for (int off = 32; off; off >>= 1) lsum += __shfl_down(lsum, off);
        if (tid == 0) atomicAdd(out + ND, lsum * (1.0f / (float)ND));
    }
    __syncthreads();
    #pragma unroll
    for (int i = 0; i < 16; ++i) {
        int item = tid + i * 256;
        int row = item >> 6, c4 = item & 63;
        int k = k_s[row];
        f32x4 v = *(const f32x4*)(cb + (size_t)k * DDIM + c4 * 4);
        __builtin_nontemporal_store(v, (f32x4*)(out + (size_t)(b0 + row) * DDIM + c4 * 4));
    }
}

extern "C" void kernel_launch(void* const* d_in, const int* in_sizes, int n_in,
                              void* d_out, int out_size, void* d_ws, size_t ws_size,
                              hipStream_t stream) {
    const float* z  = (const float*)d_in[0];   // z_e, 65536 x 256 fp32
    const float* cb = (const float*)d_in[1];   // codebook, 1024 x 256 fp32
    float* out = (float*)d_out;                // z_q (16777216) ++ loss (1)

    float*    esq_scaled = (float*)d_ws;                                  // 4 KB
    char*     cb_frag    = (char*)d_ws + 4096;                            // 256 KB
    unsigned* keys_ws    = (unsigned*)((char*)d_ws + 4096 + 262144);      // 256 KB
    float*    zsq_ws     = (float*)((char*)d_ws + 4096 + 2 * 262144);     // 256 KB

    vq_prep_kernel<<<128, 256, 0, stream>>>(cb, cb_frag, esq_scaled, out + ND, keys_ws);
    vq_argmin_kernel<<<1024, 256, 0, stream>>>(z, cb_frag, esq_scaled, keys_ws, zsq_ws);
    vq_gather_kernel<<<1024, 256, 0, stream>>>(cb, keys_ws, zsq_ws, out);
}